// Round 1
// baseline (587.496 us; speedup 1.0000x reference)
//
#include <hip/hip_runtime.h>

// Attention_884763263569 on gfx950.
// x:[65536,3,512] f32, Wk/Wv:[32,512], Wq:[32,1536], Wfc:[10,32], bfc:[10] -> out [65536,10] f32.
//
// Math folding: out = sum_t a_t * (Wfc @ Wv @ x_t) + bfc, so precompute Wvf = Wfc@Wv [10,512].
// Combined per-t weight block Wc[t] (fp16, padded to 80 rows):
//   rows  0..31 : Wk
//   rows 32..63 : Wq[:, t*512 : (t+1)*512]
//   rows 64..73 : Wvf
//   rows 74..79 : zero pad
// Main kernel: per wave, M=16 samples, GEMM vs Wc[t] via mfma_f32_16x16x32_f16,
// fused softmax+output epilogue entirely in registers (shfl over the 16 C-columns).

typedef __attribute__((ext_vector_type(4))) float  f32x4;
typedef __attribute__((ext_vector_type(8))) _Float16 h16x8;

#define T_VIEWS 3
#define D_DIM   512
#define P_DIM   32
#define C_DIM   10
#define NROWS   80        // padded combined-weight rows per t
#define M_WAVE  16        // samples per wave
#define WAVES_PER_BLOCK 4

// ---------------- Kernel A: build combined fp16 weights in d_ws ----------------
__global__ void build_weights(const float* __restrict__ Wk,
                              const float* __restrict__ Wv,
                              const float* __restrict__ Wq,
                              const float* __restrict__ Wfc,
                              _Float16* __restrict__ Wc) {
    const int row = blockIdx.x;          // 0 .. 3*80-1
    const int t   = row / NROWS;
    const int j   = row % NROWS;
    const int d   = threadIdx.x;         // 0..511
    float val;
    if (j < 32) {
        val = Wk[j * D_DIM + d];
    } else if (j < 64) {
        const int p = j - 32;
        val = Wq[p * (T_VIEWS * D_DIM) + t * D_DIM + d];
    } else if (j < 64 + C_DIM) {
        const int i = j - 64;
        float s = 0.f;
        #pragma unroll
        for (int p = 0; p < P_DIM; ++p)
            s += Wfc[i * P_DIM + p] * Wv[p * D_DIM + d];
        val = s;
    } else {
        val = 0.f;                        // pad rows: d_ws is poisoned, must zero
    }
    Wc[(size_t)row * D_DIM + d] = (_Float16)val;
}

// ---------------- Main fused kernel ----------------
__global__ __launch_bounds__(256) void attn_fused(
        const float* __restrict__ x,
        const _Float16* __restrict__ Wc,
        const float* __restrict__ bfc,
        float* __restrict__ out) {
    const int lane = threadIdx.x & 63;
    const int wave = threadIdx.x >> 6;
    const int col  = lane & 15;          // MFMA col (A-row m / B-row n / C-col)
    const int quad = lane >> 4;          // MFMA k-group / C row-group
    const int row_base = blockIdx.x * (M_WAVE * WAVES_PER_BLOCK) + wave * M_WAVE;

    // acc[t][ntile]: C-fragments; ntile 0,1 = k_t cols 0..31, 2,3 = qpart_t, 4 = y_t (+pad)
    f32x4 acc[3][5];
    #pragma unroll
    for (int t = 0; t < 3; ++t)
        #pragma unroll
        for (int n = 0; n < 5; ++n)
            acc[t][n] = (f32x4)0.f;

    // A-operand: lane holds x[m=col][k = quad*8 + j], 8 contiguous fp32 from HBM.
    const float* xrow = x + (size_t)(row_base + col) * (T_VIEWS * D_DIM) + quad * 8;

    #pragma unroll
    for (int t = 0; t < 3; ++t) {
        const float* xt = xrow + t * D_DIM;
        const _Float16* wt = Wc + ((size_t)t * NROWS + col) * D_DIM + quad * 8;
        #pragma unroll 4
        for (int kc = 0; kc < 16; ++kc) {
            const f32x4 x0 = *(const f32x4*)(xt + kc * 32);
            const f32x4 x1 = *(const f32x4*)(xt + kc * 32 + 4);
            h16x8 a;
            #pragma unroll
            for (int i = 0; i < 4; ++i) {
                a[i]     = (_Float16)x0[i];
                a[i + 4] = (_Float16)x1[i];
            }
            #pragma unroll
            for (int n = 0; n < 5; ++n) {
                const h16x8 b = *(const h16x8*)(wt + kc * 32 + (size_t)n * 16 * D_DIM);
                acc[t][n] = __builtin_amdgcn_mfma_f32_16x16x32_f16(a, b, acc[t][n], 0, 0, 0);
            }
        }
    }

    // ---------------- Epilogue (registers + shfl only) ----------------
    // C layout: element r of acc holds row (quad*4 + r), column (ntile*16 + col).
    const float bias = (col < C_DIM) ? bfc[col] : 0.f;

    float outv[4];
    #pragma unroll
    for (int r = 0; r < 4; ++r) {
        // q_p for p=col (tiles n=2) and p=16+col (tiles n=3), summed over t
        const float qa = acc[0][2][r] + acc[1][2][r] + acc[2][2][r];
        const float qb = acc[0][3][r] + acc[1][3][r] + acc[2][3][r];
        // per-lane partial of score_t = sum_p q_p * k_t[p]
        float s0 = qa * acc[0][0][r] + qb * acc[0][1][r];
        float s1 = qa * acc[1][0][r] + qb * acc[1][1][r];
        float s2 = qa * acc[2][0][r] + qb * acc[2][1][r];
        // reduce across the 16 columns (masks 1,2,4,8 stay inside the 16-lane group)
        #pragma unroll
        for (int m = 1; m <= 8; m <<= 1) {
            s0 += __shfl_xor(s0, m, 64);
            s1 += __shfl_xor(s1, m, 64);
            s2 += __shfl_xor(s2, m, 64);
        }
        const float mx = fmaxf(s0, fmaxf(s1, s2));
        const float e0 = __expf(s0 - mx);
        const float e1 = __expf(s1 - mx);
        const float e2 = __expf(s2 - mx);
        const float inv = 1.f / (e0 + e1 + e2);
        outv[r] = (e0 * acc[0][4][r] + e1 * acc[1][4][r] + e2 * acc[2][4][r]) * inv + bias;
    }

    if (col < C_DIM) {
        const int b0 = row_base + quad * 4;
        #pragma unroll
        for (int r = 0; r < 4; ++r)
            out[(size_t)(b0 + r) * C_DIM + col] = outv[r];
    }
}

extern "C" void kernel_launch(void* const* d_in, const int* in_sizes, int n_in,
                              void* d_out, int out_size, void* d_ws, size_t ws_size,
                              hipStream_t stream) {
    const float* x   = (const float*)d_in[0];
    const float* Wk  = (const float*)d_in[1];
    const float* Wv  = (const float*)d_in[2];
    const float* Wq  = (const float*)d_in[3];
    const float* Wfc = (const float*)d_in[4];
    const float* bfc = (const float*)d_in[5];
    _Float16* Wc = (_Float16*)d_ws;       // 3*80*512 halfs = 240 KB

    hipLaunchKernelGGL(build_weights, dim3(T_VIEWS * NROWS), dim3(D_DIM), 0, stream,
                       Wk, Wv, Wq, Wfc, Wc);

    const int B_TOTAL = in_sizes[0] / (T_VIEWS * D_DIM);   // 65536
    const int blocks = B_TOTAL / (M_WAVE * WAVES_PER_BLOCK); // 1024
    hipLaunchKernelGGL(attn_fused, dim3(blocks), dim3(256), 0, stream,
                       x, Wc, bfc, (float*)d_out);
}

// Round 2
// 536.723 us; speedup vs baseline: 1.0946x; 1.0946x over previous
//
#include <hip/hip_runtime.h>

// Attention_884763263569 on gfx950 — v2.
// x:[65536,3,512] f32, Wk/Wv:[32,512], Wq:[32,1536], Wfc:[10,32], bfc:[10] -> out [65536,10] f32.
//
// Folding: out = sum_t a_t * (Wfc@Wv @ x_t) + bfc  ->  Wvf = Wfc@Wv [10,512].
// Combined per-t logical weight rows (80, fp16): 0..31 Wk | 32..63 Wq slice t | 64..73 Wvf | 74..79 zero.
// v2: weights stored in global in MFMA-FRAGMENT ORDER [t][kc][n][lane][8] so the
// main kernel's B-loads are linear (base + lane*16). M=32 samples/wave (2 M-tiles
// share every B-fragment). Zero LDS, zero barriers.

typedef __attribute__((ext_vector_type(4))) float  f32x4;
typedef __attribute__((ext_vector_type(8))) _Float16 h16x8;

#define T_VIEWS 3
#define D_DIM   512
#define P_DIM   32
#define C_DIM   10
#define NROWS   80          // padded logical rows per t
#define NT      5           // n-tiles of 16
#define KC      16          // k-chunks of 32
#define M_TILES 2           // 16-row M-tiles per wave
#define M_WAVE  (M_TILES*16)
#define WAVES_PER_BLOCK 4
#define SAMPLES_PER_BLOCK (M_WAVE*WAVES_PER_BLOCK)   // 128

// ---------------- Kernel A: build fragment-ordered fp16 weights in d_ws ----------------
// One thread per output half. Logical (t, j, d) -> frag addr (((t*KC+kc)*NT+n)*64 + quad*16+col)*8 + jj
__global__ void build_weights(const float* __restrict__ Wk,
                              const float* __restrict__ Wv,
                              const float* __restrict__ Wq,
                              const float* __restrict__ Wfc,
                              _Float16* __restrict__ Wf) {
    const int row = blockIdx.x;          // 0 .. 3*80-1
    const int t   = row / NROWS;
    const int j   = row % NROWS;
    const int d   = threadIdx.x;         // 0..511
    float val;
    if (j < 32) {
        val = Wk[j * D_DIM + d];
    } else if (j < 64) {
        const int p = j - 32;
        val = Wq[p * (T_VIEWS * D_DIM) + t * D_DIM + d];
    } else if (j < 64 + C_DIM) {
        const int i = j - 64;
        float s = 0.f;
        #pragma unroll
        for (int p = 0; p < P_DIM; ++p)
            s += Wfc[i * P_DIM + p] * Wv[p * D_DIM + d];
        val = s;
    } else {
        val = 0.f;                        // pad rows (d_ws is poisoned -> must zero)
    }
    const int n = j >> 4, col = j & 15;
    const int kc = d >> 5, r = d & 31, quad = r >> 3, jj = r & 7;
    const size_t addr = (size_t)((((t * KC + kc) * NT + n) * 64) + quad * 16 + col) * 8 + jj;
    Wf[addr] = (_Float16)val;
}

// ---------------- Main fused kernel ----------------
__global__ __launch_bounds__(256) void attn_fused(
        const float* __restrict__ x,
        const _Float16* __restrict__ Wf,
        const float* __restrict__ bfc,
        float* __restrict__ out) {
    const int lane = threadIdx.x & 63;
    const int wave = threadIdx.x >> 6;
    const int col  = lane & 15;          // MFMA: A-row m / B-col n / C-col
    const int quad = lane >> 4;          // MFMA: k-group / C row-group
    const int row_base = blockIdx.x * SAMPLES_PER_BLOCK + wave * M_WAVE;

    // acc[t][mtile][n]: n 0,1 = k_t ; 2,3 = q-part_t ; 4 = y_t (rows 0..9) + pad
    f32x4 acc[3][M_TILES][NT];
    #pragma unroll
    for (int t = 0; t < 3; ++t)
        #pragma unroll
        for (int m = 0; m < M_TILES; ++m)
            #pragma unroll
            for (int n = 0; n < NT; ++n)
                acc[t][m][n] = (f32x4)0.f;

    // A-operand base: lane (col,quad) holds x[m-row = col][k = quad*8 + j]
    const float* xbase = x + (size_t)(row_base + col) * (T_VIEWS * D_DIM) + quad * 8;

    #pragma unroll
    for (int t = 0; t < 3; ++t) {
        const _Float16* wt = Wf + (size_t)t * (KC * NT * 512) + lane * 8;
        #pragma unroll 2
        for (int kc = 0; kc < KC; ++kc) {
            h16x8 b[NT];
            #pragma unroll
            for (int n = 0; n < NT; ++n)
                b[n] = *(const h16x8*)(wt + (kc * NT + n) * 512);
            #pragma unroll
            for (int m = 0; m < M_TILES; ++m) {
                const float* xp = xbase + t * D_DIM + (size_t)m * 16 * (T_VIEWS * D_DIM) + kc * 32;
                const f32x4 x0 = __builtin_nontemporal_load((const f32x4*)xp);
                const f32x4 x1 = __builtin_nontemporal_load((const f32x4*)(xp + 4));
                h16x8 a;
                #pragma unroll
                for (int i = 0; i < 4; ++i) {
                    a[i]     = (_Float16)x0[i];
                    a[i + 4] = (_Float16)x1[i];
                }
                #pragma unroll
                for (int n = 0; n < NT; ++n)
                    acc[t][m][n] = __builtin_amdgcn_mfma_f32_16x16x32_f16(a, b[n], acc[t][m][n], 0, 0, 0);
            }
        }
    }

    // ---------------- Epilogue (registers + shfl only) ----------------
    // C layout: element r holds row (quad*4 + r), column (n*16 + col).
    const float bias = (col < C_DIM) ? bfc[col] : 0.f;

    #pragma unroll
    for (int m = 0; m < M_TILES; ++m) {
        float outv[4];
        #pragma unroll
        for (int r = 0; r < 4; ++r) {
            const float qa = acc[0][m][2][r] + acc[1][m][2][r] + acc[2][m][2][r];
            const float qb = acc[0][m][3][r] + acc[1][m][3][r] + acc[2][m][3][r];
            float s0 = qa * acc[0][m][0][r] + qb * acc[0][m][1][r];
            float s1 = qa * acc[1][m][0][r] + qb * acc[1][m][1][r];
            float s2 = qa * acc[2][m][0][r] + qb * acc[2][m][1][r];
            #pragma unroll
            for (int msk = 1; msk <= 8; msk <<= 1) {
                s0 += __shfl_xor(s0, msk, 64);
                s1 += __shfl_xor(s1, msk, 64);
                s2 += __shfl_xor(s2, msk, 64);
            }
            const float mx = fmaxf(s0, fmaxf(s1, s2));
            const float e0 = __expf(s0 - mx);
            const float e1 = __expf(s1 - mx);
            const float e2 = __expf(s2 - mx);
            const float inv = 1.f / (e0 + e1 + e2);
            outv[r] = (e0 * acc[0][m][4][r] + e1 * acc[1][m][4][r] + e2 * acc[2][m][4][r]) * inv + bias;
        }
        if (col < C_DIM) {
            const int b0 = row_base + m * 16 + quad * 4;
            #pragma unroll
            for (int r = 0; r < 4; ++r)
                out[(size_t)(b0 + r) * C_DIM + col] = outv[r];
        }
    }
}

extern "C" void kernel_launch(void* const* d_in, const int* in_sizes, int n_in,
                              void* d_out, int out_size, void* d_ws, size_t ws_size,
                              hipStream_t stream) {
    const float* x   = (const float*)d_in[0];
    const float* Wk  = (const float*)d_in[1];
    const float* Wv  = (const float*)d_in[2];
    const float* Wq  = (const float*)d_in[3];
    const float* Wfc = (const float*)d_in[4];
    const float* bfc = (const float*)d_in[5];
    _Float16* Wf = (_Float16*)d_ws;       // 3*80*512 halfs = 240 KB, fragment-ordered

    hipLaunchKernelGGL(build_weights, dim3(T_VIEWS * NROWS), dim3(D_DIM), 0, stream,
                       Wk, Wv, Wq, Wfc, Wf);

    const int B_TOTAL = in_sizes[0] / (T_VIEWS * D_DIM);      // 65536
    const int blocks = B_TOTAL / SAMPLES_PER_BLOCK;           // 512
    hipLaunchKernelGGL(attn_fused, dim3(blocks), dim3(256), 0, stream,
                       x, Wf, bfc, (float*)d_out);
}